// Round 6
// baseline (315.984 us; speedup 1.0000x reference)
//
#include <hip/hip_runtime.h>
#include <hip/hip_fp16.h>
#include <math.h>
#include <string.h>

#define Dd 192
#define Hh 192
#define Ww 192
#define K  11
#define R  5

#define TW 32             // tile width (output cols)
#define TH 16             // tile height (output rows)
#define DC 8              // output planes per chunk
#define NP (DC + 2*R)     // 18 input planes per chunk
#define NT 128            // threads per block (2 waves)
#define NQ 8              // output quads (4-col groups) per row = TW/4
#define HH_ (TH + 2*R)    // 26 halo rows
#define SQUADS 12         // staged aligned quads per row (48 cols: w0-8 .. w0+39)
#define SP 26             // stg row stride in dwords (24 data + 2 pad)
#define CS 16             // cwl row stride in dwords (8 quads * 2)
#define NSTG (HH_ * SQUADS)   // 312 staging tasks (one float4 pair each)
#define NCW  (HH_ * NQ)       // 208 conv-W tasks

struct GW { unsigned int g2[K]; };   // half2(g,g) bit patterns

static __device__ __forceinline__ __half2 u2h2(unsigned int u) {
    union { unsigned int u; __half2 h; } x; x.u = u; return x.h;
}
static __device__ __forceinline__ unsigned int h22u(__half2 h) {
    union { __half2 h; unsigned int u; } x; x.h = h; return x.u;
}
static __device__ __forceinline__ unsigned int pk(float a, float b) {
    typedef __fp16 f16x2 __attribute__((ext_vector_type(2)));
    f16x2 r = __builtin_amdgcn_cvt_pkrtz(a, b);
    union { f16x2 v; unsigned int u; } x; x.v = r; return x.u;
}

__global__ __launch_bounds__(NT, 3) void fused_ssim(
    const float* __restrict__ gr, const float* __restrict__ gt,
    GW gw, double* __restrict__ acc_g)
{
    __shared__ __align__(16) unsigned int stg[2][HH_][SP];  // x,y fp16 pairs
    __shared__ __align__(16) unsigned int cwl[5][HH_][CS];  // conv-W out, 5 fields
    __shared__ float wsum[2];

    const int tid = threadIdx.x;
    const int q   = tid & (NQ - 1);   // output quad 0..7
    const int th  = tid >> 3;         // output row 0..15
    const int w0  = blockIdx.x * TW;
    const int h0  = blockIdx.y * TH;
    const int d0  = blockIdx.z * DC;

    // ---- staging geometry: <=3 float4-pair tasks per thread ----
    int  saddr[3];     // clamped plane-local address (16B aligned)
    bool sok[3];       // row+quad fully valid
    int  srow[3], scc[3];
    bool sact[3];
#pragma unroll
    for (int k = 0; k < 3; ++k) {
        const int t = tid + k * NT;
        sact[k] = (t < NSTG);
        const int tt = sact[k] ? t : 0;
        const int r  = tt / SQUADS;
        const int cc = tt - r * SQUADS;
        srow[k] = r; scc[k] = cc;
        const int gh   = h0 - R + r;
        const bool rok = sact[k] && (gh >= 0) && (gh < Hh);
        const int ghc  = gh < 0 ? 0 : (gh >= Hh ? Hh - 1 : gh);
        const int gx0  = w0 - 8 + 4 * cc;              // aligned quad start
        const bool qok = (gx0 >= 0) && (gx0 + 3 < Ww); // quads fully in or out
        const int gxc  = gx0 < 0 ? 0 : (gx0 > Ww - 4 ? Ww - 4 : gx0);
        saddr[k] = ghc * Ww + gxc;
        sok[k]   = rok && qok;
    }

    float4 px[3], py[3];

    // ---- prologue: load input plane ip=0 ----
    {
        const int z = d0 - R;
        const bool zok = (z >= 0);
        const int zb = (zok ? z : 0) * Hh * Ww;
#pragma unroll
        for (int k = 0; k < 3; ++k) {
            const float4 vx = *(const float4*)(gr + zb + saddr[k]);
            const float4 vy = *(const float4*)(gt + zb + saddr[k]);
            const bool ok = sok[k] && zok;
            px[k].x = ok ? vx.x : -1.f; px[k].y = ok ? vx.y : -1.f;
            px[k].z = ok ? vx.z : -1.f; px[k].w = ok ? vx.w : -1.f;
            py[k].x = ok ? vy.x : -1.f; py[k].y = ok ? vy.y : -1.f;
            py[k].z = ok ? vy.z : -1.f; py[k].w = ok ? vy.w : -1.f;
        }
    }

    // conv-D accumulators: DC output planes x 5 fields x 4 cols (fp16 pairs)
    unsigned int acc[DC][5][2];
#pragma unroll
    for (int od = 0; od < DC; ++od)
#pragma unroll
        for (int f = 0; f < 5; ++f) { acc[od][f][0] = 0u; acc[od][f][1] = 0u; }

    float ssim_acc = 0.0f;

#pragma unroll
    for (int ip = 0; ip < NP; ++ip) {
        // (A) staged regs -> LDS (rescale + fp16 pack), b64 writes
#pragma unroll
        for (int k = 0; k < 3; ++k) if (sact[k]) {
            uint2 vx, vy;
            vx.x = pk(fmaf(px[k].x, .5f, .5f), fmaf(px[k].y, .5f, .5f));
            vx.y = pk(fmaf(px[k].z, .5f, .5f), fmaf(px[k].w, .5f, .5f));
            vy.x = pk(fmaf(py[k].x, .5f, .5f), fmaf(py[k].y, .5f, .5f));
            vy.y = pk(fmaf(py[k].z, .5f, .5f), fmaf(py[k].w, .5f, .5f));
            *(uint2*)&stg[0][srow[k]][2 * scc[k]] = vx;
            *(uint2*)&stg[1][srow[k]][2 * scc[k]] = vy;
        }
        __syncthreads();

        // (C) prefetch next plane (consumed next iteration)
        if (ip < NP - 1) {
            const int z = d0 - R + ip + 1;
            const bool zok = (z >= 0) && (z < Dd);
            const int zb = (zok ? z : 0) * Hh * Ww;
#pragma unroll
            for (int k = 0; k < 3; ++k) {
                const float4 vx = *(const float4*)(gr + zb + saddr[k]);
                const float4 vy = *(const float4*)(gt + zb + saddr[k]);
                const bool ok = sok[k] && zok;
                px[k].x = ok ? vx.x : -1.f; px[k].y = ok ? vx.y : -1.f;
                px[k].z = ok ? vx.z : -1.f; px[k].w = ok ? vx.w : -1.f;
                py[k].x = ok ? vy.x : -1.f; py[k].y = ok ? vy.y : -1.f;
                py[k].z = ok ? vy.z : -1.f; py[k].w = ok ? vy.w : -1.f;
            }
        }

        // (D) conv-W: on-the-fly products, b64 LDS traffic
#pragma unroll
        for (int k2 = 0; k2 < 2; ++k2) {
            const int t = tid + k2 * NT;
            if (t < NCW) {
                const int r  = t >> 3;
                const int qq = t & (NQ - 1);
                unsigned int dx[10], dy[10];
#pragma unroll
                for (int u = 0; u < 5; ++u) {
                    const uint2 vx = *(const uint2*)&stg[0][r][2 * qq + 2 * u];
                    const uint2 vy = *(const uint2*)&stg[1][r][2 * qq + 2 * u];
                    dx[2 * u] = vx.x; dx[2 * u + 1] = vx.y;
                    dy[2 * u] = vy.x; dy[2 * u + 1] = vy.y;
                }
                __half2 aA[5], aB[5];
#pragma unroll
                for (int f = 0; f < 5; ++f) { aA[f] = u2h2(0u); aB[f] = u2h2(0u); }
#pragma unroll
                for (int t5 = 0; t5 < K; ++t5) {
                    const int b = t5 + 3;      // starting half index (window @ -8)
                    unsigned int xa, xb, ya, yb;
                    if ((b & 1) == 0) {
                        xa = dx[b >> 1]; xb = dx[(b >> 1) + 1];
                        ya = dy[b >> 1]; yb = dy[(b >> 1) + 1];
                    } else {
                        xa = __builtin_amdgcn_alignbit(dx[(b + 1) >> 1], dx[b >> 1], 16);
                        xb = __builtin_amdgcn_alignbit(dx[(b + 3) >> 1], dx[(b + 1) >> 1], 16);
                        ya = __builtin_amdgcn_alignbit(dy[(b + 1) >> 1], dy[b >> 1], 16);
                        yb = __builtin_amdgcn_alignbit(dy[(b + 3) >> 1], dy[(b + 1) >> 1], 16);
                    }
                    const __half2 g   = u2h2(gw.g2[t5]);
                    const __half2 hxa = u2h2(xa), hxb = u2h2(xb);
                    const __half2 hya = u2h2(ya), hyb = u2h2(yb);
                    aA[0] = __hfma2(g, hxa, aA[0]);  aB[0] = __hfma2(g, hxb, aB[0]);
                    aA[1] = __hfma2(g, hya, aA[1]);  aB[1] = __hfma2(g, hyb, aB[1]);
                    aA[2] = __hfma2(g, __hmul2(hxa, hxa), aA[2]);
                    aB[2] = __hfma2(g, __hmul2(hxb, hxb), aB[2]);
                    aA[3] = __hfma2(g, __hmul2(hya, hya), aA[3]);
                    aB[3] = __hfma2(g, __hmul2(hyb, hyb), aB[3]);
                    aA[4] = __hfma2(g, __hmul2(hxa, hya), aA[4]);
                    aB[4] = __hfma2(g, __hmul2(hxb, hyb), aB[4]);
                }
#pragma unroll
                for (int f = 0; f < 5; ++f) {
                    uint2 o; o.x = h22u(aA[f]); o.y = h22u(aB[f]);
                    *(uint2*)&cwl[f][r][2 * qq] = o;
                }
            }
        }
        __syncthreads();

        // (F) conv-H (b64 reads) -> direct conv-D accumulation
        __half2 cA[5], cB[5];
#pragma unroll
        for (int f = 0; f < 5; ++f) { cA[f] = u2h2(0u); cB[f] = u2h2(0u); }
#pragma unroll
        for (int t6 = 0; t6 < K; ++t6) {
            const __half2 g = u2h2(gw.g2[t6]);
#pragma unroll
            for (int f = 0; f < 5; ++f) {
                const uint2 v = *(const uint2*)&cwl[f][th + t6][2 * q];
                cA[f] = __hfma2(g, u2h2(v.x), cA[f]);
                cB[f] = __hfma2(g, u2h2(v.y), cB[f]);
            }
        }

        // conv-D: plane ip contributes g[ip-od] to output plane od
#pragma unroll
        for (int od = 0; od < DC; ++od) {
            const int tz = ip - od;
            if (tz >= 0 && tz < K) {          // static after unroll
                const __half2 g = u2h2(gw.g2[tz]);
#pragma unroll
                for (int f = 0; f < 5; ++f) {
                    acc[od][f][0] = h22u(__hfma2(g, cA[f], u2h2(acc[od][f][0])));
                    acc[od][f][1] = h22u(__hfma2(g, cB[f], u2h2(acc[od][f][1])));
                }
            }
        }

        // eager SSIM eval: acc[ip-10] is complete
        if (ip >= 2 * R) {
            const int od = ip - 2 * R;
            const float C1 = 1e-4f, C2 = 9e-4f;
#pragma unroll
            for (int hv = 0; hv < 2; ++hv) {
                const __half2 v0 = u2h2(acc[od][0][hv]);
                const __half2 v1 = u2h2(acc[od][1][hv]);
                const __half2 v2 = u2h2(acc[od][2][hv]);
                const __half2 v3 = u2h2(acc[od][3][hv]);
                const __half2 v4 = u2h2(acc[od][4][hv]);
#pragma unroll
                for (int col = 0; col < 2; ++col) {
                    const float m1  = col ? __high2float(v0) : __low2float(v0);
                    const float m2  = col ? __high2float(v1) : __low2float(v1);
                    const float e11 = col ? __high2float(v2) : __low2float(v2);
                    const float e22 = col ? __high2float(v3) : __low2float(v3);
                    const float e12 = col ? __high2float(v4) : __low2float(v4);
                    const float mu1sq = m1 * m1, mu2sq = m2 * m2, mu12 = m1 * m2;
                    const float s11 = e11 - mu1sq;
                    const float s22 = e22 - mu2sq;
                    const float s12 = e12 - mu12;
                    const float num = (2.f * mu12 + C1) * (2.f * s12 + C2);
                    const float den = (mu1sq + mu2sq + C1) * (s11 + s22 + C2);
                    ssim_acc += num * __builtin_amdgcn_rcpf(den);
                }
            }
        }
    }

    // ---- block reduction + one atomic ----
    float v = ssim_acc;
#pragma unroll
    for (int o = 32; o > 0; o >>= 1) v += __shfl_down(v, o);
    const int lane = tid & 63;
    const int wid  = tid >> 6;
    if (lane == 0) wsum[wid] = v;
    __syncthreads();
    if (tid == 0) atomicAdd(acc_g, (double)(wsum[0] + wsum[1]));
}

__global__ void k4_final(const double* __restrict__ acc, float* __restrict__ out) {
    if (threadIdx.x == 0) {
        const double n = (double)((size_t)Dd * Hh * Ww);
        out[0] = (float)(1.0 - (*acc) / n);
    }
}

// host-side float -> half (RNE)
static unsigned short f2h(float x) {
    unsigned int u; memcpy(&u, &x, 4);
    unsigned int s = (u >> 16) & 0x8000u;
    int e = (int)((u >> 23) & 0xffu) - 112;
    unsigned int m = u & 0x7fffffu;
    if (e <= 0) return (unsigned short)s;
    unsigned int mant = m + 0xFFFu + ((m >> 13) & 1u);
    if (mant & 0x800000u) { mant = 0; e += 1; }
    return (unsigned short)(s | ((unsigned)e << 10) | (mant >> 13));
}

extern "C" void kernel_launch(void* const* d_in, const int* in_sizes, int n_in,
                              void* d_out, int out_size, void* d_ws, size_t ws_size,
                              hipStream_t stream) {
    const float* gr = (const float*)d_in[0];
    const float* gt = (const float*)d_in[1];
    float* out = (float*)d_out;

    // 1D normalized gaussian (exact outer-product factorization of the 3D window)
    GW gw;
    {
        double e[K], s = 0.0;
        for (int i = 0; i < K; ++i) {
            const double a = (double)((i - R) * (i - R));
            e[i] = exp(-a / (2.0 * 1.5 * 1.5));
            s += e[i];
        }
        for (int i = 0; i < K; ++i) {
            unsigned short h = f2h((float)(e[i] / s));
            gw.g2[i] = (unsigned int)h | ((unsigned int)h << 16);
        }
    }

    double* acc = (double*)d_ws;
    (void)hipMemsetAsync(d_ws, 0, sizeof(double), stream);

    dim3 grid(Ww / TW, Hh / TH, Dd / DC);   // 6 x 12 x 24 = 1728 blocks
    fused_ssim<<<grid, NT, 0, stream>>>(gr, gt, gw, acc);

    k4_final<<<1, 64, 0, stream>>>(acc, out);
}

// Round 7
// 122.959 us; speedup vs baseline: 2.5698x; 2.5698x over previous
//
#include <hip/hip_runtime.h>
#include <hip/hip_fp16.h>
#include <math.h>
#include <string.h>

#define Dd 192
#define Hh 192
#define Ww 192
#define K  11
#define R  5

#define TW 32             // tile width (output cols)
#define TH 16             // tile height (output rows)
#define DC 12             // output planes per chunk (22 input planes = 2*11)
#define NP 22             // input planes per chunk
#define NT 256            // threads per block (4 waves)
#define NQ 8              // output quads (4-col groups) per row = TW/4
#define HH_ 26            // halo rows = TH + 2R
#define SQUADS 12         // staged aligned quads per row (48 cols: w0-8 .. w0+39)
#define SP 26             // stg row stride in dwords (24 data + 2 pad)
#define CS 16             // cwl row stride in dwords (8 quads * 2)
#define NSTG (HH_ * SQUADS)   // 312 staging tasks (one float4 pair each)
#define NCW  (HH_ * NQ)       // 208 conv-W tasks

struct GW { unsigned int g2[K]; };   // half2(g,g) bit patterns

static __device__ __forceinline__ __half2 u2h2(unsigned int u) {
    union { unsigned int u; __half2 h; } x; x.u = u; return x.h;
}
static __device__ __forceinline__ unsigned int h22u(__half2 h) {
    union { __half2 h; unsigned int u; } x; x.h = h; return x.u;
}
static __device__ __forceinline__ unsigned int pk(float a, float b) {
    typedef __fp16 f16x2 __attribute__((ext_vector_type(2)));
    f16x2 r = __builtin_amdgcn_cvt_pkrtz(a, b);
    union { f16x2 v; unsigned int u; } x; x.v = r; return x.u;
}

__global__ __launch_bounds__(NT, 2) void fused_ssim(
    const float* __restrict__ gr, const float* __restrict__ gt,
    GW gw, double* __restrict__ acc_g)
{
    __shared__ __align__(16) unsigned int stg[2][HH_][SP];  // x,y fp16 pairs
    __shared__ __align__(16) unsigned int cwl[5][HH_][CS];  // conv-W out, 5 fields
    __shared__ float wsum[NT / 64];

    const int tid = threadIdx.x;
    const int q   = tid & (NQ - 1);   // output quad 0..7 (tid<128 path)
    const int th  = (tid >> 3) & 15;  // output row 0..15 (tid<128 path)
    const int w0  = blockIdx.x * TW;
    const int h0  = blockIdx.y * TH;
    const int d0  = blockIdx.z * DC;

    // ---- staging geometry: <=2 float4-pair tasks per thread ----
    int  saddr[2];     // clamped plane-local address (16B aligned)
    bool sok[2];       // row+quad fully valid
    int  srow[2], scc[2];
    bool sact[2];
#pragma unroll
    for (int k = 0; k < 2; ++k) {
        const int t = tid + k * NT;
        sact[k] = (t < NSTG);
        const int tt = sact[k] ? t : 0;
        const int r  = tt / SQUADS;
        const int cc = tt - r * SQUADS;
        srow[k] = r; scc[k] = cc;
        const int gh   = h0 - R + r;
        const bool rok = sact[k] && (gh >= 0) && (gh < Hh);
        const int ghc  = gh < 0 ? 0 : (gh >= Hh ? Hh - 1 : gh);
        const int gx0  = w0 - 8 + 4 * cc;              // aligned quad start
        const bool qok = (gx0 >= 0) && (gx0 + 3 < Ww); // quads fully in or out
        const int gxc  = gx0 < 0 ? 0 : (gx0 > Ww - 4 ? Ww - 4 : gx0);
        saddr[k] = ghc * Ww + gxc;
        sok[k]   = rok && qok;
    }

    float4 px[2], py[2];

    // ---- prologue: load input plane ip=0 ----
    {
        const int z = d0 - R;
        const bool zok = (z >= 0);
        const int zb = (zok ? z : 0) * Hh * Ww;
#pragma unroll
        for (int k = 0; k < 2; ++k) {
            const float4 vx = *(const float4*)(gr + zb + saddr[k]);
            const float4 vy = *(const float4*)(gt + zb + saddr[k]);
            const bool ok = sok[k] && zok;
            px[k].x = ok ? vx.x : -1.f; px[k].y = ok ? vx.y : -1.f;
            px[k].z = ok ? vx.z : -1.f; px[k].w = ok ? vx.w : -1.f;
            py[k].x = ok ? vy.x : -1.f; py[k].y = ok ? vy.y : -1.f;
            py[k].z = ok ? vy.z : -1.f; py[k].w = ok ? vy.w : -1.f;
        }
    }

    unsigned int hist[K][5][2];   // conv-D ring: 11 planes x 5 fields x 4 cols
#pragma unroll
    for (int t = 0; t < K; ++t)
#pragma unroll
        for (int f = 0; f < 5; ++f) { hist[t][f][0] = 0u; hist[t][f][1] = 0u; }

    float ssim_acc = 0.0f;

    for (int c = 0; c < 2; ++c) {
#pragma unroll
        for (int j = 0; j < K; ++j) {
            const int iz = c * K + j;

            // (A) staged regs -> LDS (rescale + fp16 pack), b64 writes
#pragma unroll
            for (int k = 0; k < 2; ++k) if (sact[k]) {
                uint2 vx, vy;
                vx.x = pk(fmaf(px[k].x, .5f, .5f), fmaf(px[k].y, .5f, .5f));
                vx.y = pk(fmaf(px[k].z, .5f, .5f), fmaf(px[k].w, .5f, .5f));
                vy.x = pk(fmaf(py[k].x, .5f, .5f), fmaf(py[k].y, .5f, .5f));
                vy.y = pk(fmaf(py[k].z, .5f, .5f), fmaf(py[k].w, .5f, .5f));
                *(uint2*)&stg[0][srow[k]][2 * scc[k]] = vx;
                *(uint2*)&stg[1][srow[k]][2 * scc[k]] = vy;
            }
            __syncthreads();

            // (C) prefetch next plane (consumed next iteration)
            if (iz < NP - 1) {
                const int z = d0 - R + iz + 1;
                const bool zok = (z >= 0) && (z < Dd);
                const int zb = (zok ? z : 0) * Hh * Ww;
#pragma unroll
                for (int k = 0; k < 2; ++k) {
                    const float4 vx = *(const float4*)(gr + zb + saddr[k]);
                    const float4 vy = *(const float4*)(gt + zb + saddr[k]);
                    const bool ok = sok[k] && zok;
                    px[k].x = ok ? vx.x : -1.f; px[k].y = ok ? vx.y : -1.f;
                    px[k].z = ok ? vx.z : -1.f; px[k].w = ok ? vx.w : -1.f;
                    py[k].x = ok ? vy.x : -1.f; py[k].y = ok ? vy.y : -1.f;
                    py[k].z = ok ? vy.z : -1.f; py[k].w = ok ? vy.w : -1.f;
                }
            }

            // (D) conv-W: on-the-fly products, b64 LDS traffic (single pass)
            if (tid < NCW) {
                const int r  = tid >> 3;
                const int qq = tid & (NQ - 1);
                unsigned int dx[10], dy[10];
#pragma unroll
                for (int u = 0; u < 5; ++u) {
                    const uint2 vx = *(const uint2*)&stg[0][r][2 * qq + 2 * u];
                    const uint2 vy = *(const uint2*)&stg[1][r][2 * qq + 2 * u];
                    dx[2 * u] = vx.x; dx[2 * u + 1] = vx.y;
                    dy[2 * u] = vy.x; dy[2 * u + 1] = vy.y;
                }
                __half2 aA[5], aB[5];
#pragma unroll
                for (int f = 0; f < 5; ++f) { aA[f] = u2h2(0u); aB[f] = u2h2(0u); }
#pragma unroll
                for (int t5 = 0; t5 < K; ++t5) {
                    const int b = t5 + 3;      // starting half index (window @ -8)
                    unsigned int xa, xb, ya, yb;
                    if ((b & 1) == 0) {
                        xa = dx[b >> 1]; xb = dx[(b >> 1) + 1];
                        ya = dy[b >> 1]; yb = dy[(b >> 1) + 1];
                    } else {
                        xa = __builtin_amdgcn_alignbit(dx[(b + 1) >> 1], dx[b >> 1], 16);
                        xb = __builtin_amdgcn_alignbit(dx[(b + 3) >> 1], dx[(b + 1) >> 1], 16);
                        ya = __builtin_amdgcn_alignbit(dy[(b + 1) >> 1], dy[b >> 1], 16);
                        yb = __builtin_amdgcn_alignbit(dy[(b + 3) >> 1], dy[(b + 1) >> 1], 16);
                    }
                    const __half2 g   = u2h2(gw.g2[t5]);
                    const __half2 hxa = u2h2(xa), hxb = u2h2(xb);
                    const __half2 hya = u2h2(ya), hyb = u2h2(yb);
                    aA[0] = __hfma2(g, hxa, aA[0]);  aB[0] = __hfma2(g, hxb, aB[0]);
                    aA[1] = __hfma2(g, hya, aA[1]);  aB[1] = __hfma2(g, hyb, aB[1]);
                    aA[2] = __hfma2(g, __hmul2(hxa, hxa), aA[2]);
                    aB[2] = __hfma2(g, __hmul2(hxb, hxb), aB[2]);
                    aA[3] = __hfma2(g, __hmul2(hya, hya), aA[3]);
                    aB[3] = __hfma2(g, __hmul2(hyb, hyb), aB[3]);
                    aA[4] = __hfma2(g, __hmul2(hxa, hya), aA[4]);
                    aB[4] = __hfma2(g, __hmul2(hxb, hyb), aB[4]);
                }
#pragma unroll
                for (int f = 0; f < 5; ++f) {
                    uint2 o; o.x = h22u(aA[f]); o.y = h22u(aB[f]);
                    *(uint2*)&cwl[f][r][2 * qq] = o;
                }
            }
            __syncthreads();

            // (F) conv-H (4-col b64 reads, threads 0..127) -> ring -> conv-D/SSIM
            if (tid < TH * NQ) {
                __half2 cA[5], cB[5];
#pragma unroll
                for (int f = 0; f < 5; ++f) { cA[f] = u2h2(0u); cB[f] = u2h2(0u); }
#pragma unroll
                for (int t6 = 0; t6 < K; ++t6) {
                    const __half2 g = u2h2(gw.g2[t6]);
#pragma unroll
                    for (int f = 0; f < 5; ++f) {
                        const uint2 v = *(const uint2*)&cwl[f][th + t6][2 * q];
                        cA[f] = __hfma2(g, u2h2(v.x), cA[f]);
                        cB[f] = __hfma2(g, u2h2(v.y), cB[f]);
                    }
                }
#pragma unroll
                for (int f = 0; f < 5; ++f) {
                    hist[j][f][0] = h22u(cA[f]);
                    hist[j][f][1] = h22u(cB[f]);
                }

                // conv-D + SSIM once the ring is full
                if (iz >= 2 * R) {
                    __half2 sA[5], sB[5];
#pragma unroll
                    for (int f = 0; f < 5; ++f) { sA[f] = u2h2(0u); sB[f] = u2h2(0u); }
#pragma unroll
                    for (int t7 = 0; t7 < K; ++t7) {
                        const int s = (j + 1 + t7) % K;   // static after unroll
                        const __half2 g = u2h2(gw.g2[t7]);
#pragma unroll
                        for (int f = 0; f < 5; ++f) {
                            sA[f] = __hfma2(g, u2h2(hist[s][f][0]), sA[f]);
                            sB[f] = __hfma2(g, u2h2(hist[s][f][1]), sB[f]);
                        }
                    }
                    const float C1 = 1e-4f, C2 = 9e-4f;
#pragma unroll
                    for (int hv = 0; hv < 2; ++hv) {
                        const __half2 v0 = hv ? sB[0] : sA[0];
                        const __half2 v1 = hv ? sB[1] : sA[1];
                        const __half2 v2 = hv ? sB[2] : sA[2];
                        const __half2 v3 = hv ? sB[3] : sA[3];
                        const __half2 v4 = hv ? sB[4] : sA[4];
#pragma unroll
                        for (int col = 0; col < 2; ++col) {
                            const float m1  = col ? __high2float(v0) : __low2float(v0);
                            const float m2  = col ? __high2float(v1) : __low2float(v1);
                            const float e11 = col ? __high2float(v2) : __low2float(v2);
                            const float e22 = col ? __high2float(v3) : __low2float(v3);
                            const float e12 = col ? __high2float(v4) : __low2float(v4);
                            const float mu1sq = m1 * m1, mu2sq = m2 * m2, mu12 = m1 * m2;
                            const float s11 = e11 - mu1sq;
                            const float s22 = e22 - mu2sq;
                            const float s12 = e12 - mu12;
                            const float num = (2.f * mu12 + C1) * (2.f * s12 + C2);
                            const float den = (mu1sq + mu2sq + C1) * (s11 + s22 + C2);
                            ssim_acc += num * __builtin_amdgcn_rcpf(den);
                        }
                    }
                }
            }
        }
    }

    // ---- block reduction + one atomic ----
    float v = ssim_acc;
#pragma unroll
    for (int o = 32; o > 0; o >>= 1) v += __shfl_down(v, o);
    const int lane = tid & 63;
    const int wid  = tid >> 6;
    if (lane == 0) wsum[wid] = v;
    __syncthreads();
    if (tid == 0) {
        float s = 0.f;
#pragma unroll
        for (int i = 0; i < NT / 64; ++i) s += wsum[i];
        atomicAdd(acc_g, (double)s);
    }
}

__global__ void k4_final(const double* __restrict__ acc, float* __restrict__ out) {
    if (threadIdx.x == 0) {
        const double n = (double)((size_t)Dd * Hh * Ww);
        out[0] = (float)(1.0 - (*acc) / n);
    }
}

// host-side float -> half (RNE)
static unsigned short f2h(float x) {
    unsigned int u; memcpy(&u, &x, 4);
    unsigned int s = (u >> 16) & 0x8000u;
    int e = (int)((u >> 23) & 0xffu) - 112;
    unsigned int m = u & 0x7fffffu;
    if (e <= 0) return (unsigned short)s;
    unsigned int mant = m + 0xFFFu + ((m >> 13) & 1u);
    if (mant & 0x800000u) { mant = 0; e += 1; }
    return (unsigned short)(s | ((unsigned)e << 10) | (mant >> 13));
}

extern "C" void kernel_launch(void* const* d_in, const int* in_sizes, int n_in,
                              void* d_out, int out_size, void* d_ws, size_t ws_size,
                              hipStream_t stream) {
    const float* gr = (const float*)d_in[0];
    const float* gt = (const float*)d_in[1];
    float* out = (float*)d_out;

    // 1D normalized gaussian (exact outer-product factorization of the 3D window)
    GW gw;
    {
        double e[K], s = 0.0;
        for (int i = 0; i < K; ++i) {
            const double a = (double)((i - R) * (i - R));
            e[i] = exp(-a / (2.0 * 1.5 * 1.5));
            s += e[i];
        }
        for (int i = 0; i < K; ++i) {
            unsigned short h = f2h((float)(e[i] / s));
            gw.g2[i] = (unsigned int)h | ((unsigned int)h << 16);
        }
    }

    double* acc = (double*)d_ws;
    (void)hipMemsetAsync(d_ws, 0, sizeof(double), stream);

    dim3 grid(Ww / TW, Hh / TH, Dd / DC);   // 6 x 12 x 16 = 1152 blocks
    fused_ssim<<<grid, NT, 0, stream>>>(gr, gt, gw, acc);

    k4_final<<<1, 64, 0, stream>>>(acc, out);
}